// Round 11
// baseline (90.404 us; speedup 1.0000x reference)
//
#include <hip/hip_runtime.h>

typedef __attribute__((ext_vector_type(8))) short bf16x8;
typedef __attribute__((ext_vector_type(4))) float f32x4;
typedef __attribute__((ext_vector_type(16))) float f32x16;
typedef __attribute__((ext_vector_type(2))) unsigned int u32x2;

#define DEVI static __device__ __forceinline__

namespace {
constexpr int NSEQ = 2048, NH = 16;
constexpr int D = 1024, D3 = 3072;
}

DEVI unsigned short f2bf(float f) {
  union { float f; unsigned int u; } v; v.f = f;
  unsigned int r = v.u + 0x7FFFu + ((v.u >> 16) & 1u);
  return (unsigned short)(r >> 16);
}

DEVI void gload16(const unsigned short* g, unsigned short* lds_) {
  __builtin_amdgcn_global_load_lds(
      (const __attribute__((address_space(1))) unsigned int*)g,
      (__attribute__((address_space(3))) unsigned int*)lds_, 16, 0, 0);
}

DEVI f32x4 mfma16(bf16x8 a, bf16x8 b, f32x4 c) {
  return __builtin_amdgcn_mfma_f32_16x16x32_bf16(a, b, c, 0, 0, 0);
}

DEVI f32x16 mfma32(bf16x8 a, bf16x8 b, f32x16 c) {
  return __builtin_amdgcn_mfma_f32_32x32x16_bf16(a, b, c, 0, 0, 0);
}

DEVI float exp2g(float x) {
#if __has_builtin(__builtin_amdgcn_exp2f)
  return __builtin_amdgcn_exp2f(x);
#else
  return exp2f(x);
#endif
}

DEVI unsigned int cvtpk(float a, float b) {
  unsigned int r;
  asm("v_cvt_pk_bf16_f32 %0, %1, %2" : "=v"(r) : "v"(a), "v"(b));
  return r;
}

DEVI u32x2 pswap2(unsigned int a, unsigned int b) {
  return __builtin_amdgcn_permlane32_swap(a, b, false, false);
}
DEVI float xmax_halves(float v) {
  union { float f; unsigned int u; } c; c.f = v;
  u32x2 r = pswap2(c.u, c.u);
  union { unsigned int u; float f; } x, y; x.u = r.x; y.u = r.y;
  return fmaxf(x.f, y.f);
}

union U4 { unsigned int u[4]; bf16x8 v; };

// ---------------- prep: cast x -> bf16  +  transpose/cast W -> Wt ----------
__global__ __launch_bounds__(256) void prep_k(const float* __restrict__ x,
                                              const float* __restrict__ W,
                                              unsigned short* __restrict__ xb,
                                              unsigned short* __restrict__ Wt) {
  __shared__ float t[32][33];
  const int bid = blockIdx.x;
  if (bid < 4096) {
    int i = (bid * 256 + threadIdx.x) * 4;
    float4 v = *reinterpret_cast<const float4*>(x + i);
    ushort4 o;
    o.x = f2bf(v.x); o.y = f2bf(v.y); o.z = f2bf(v.z); o.w = f2bf(v.w);
    *reinterpret_cast<ushort4*>(xb + i) = o;
  } else {
    const int b2 = bid - 4096;
    const int c0 = (b2 % 96) * 32, k0 = (b2 / 96) * 32;
    const int tx = threadIdx.x & 31, ty = threadIdx.x >> 5;  // ty 0..7
#pragma unroll
    for (int r = 0; r < 32; r += 8)
      t[ty + r][tx] = W[(size_t)(k0 + ty + r) * D3 + c0 + tx];
    __syncthreads();
#pragma unroll
    for (int r = 0; r < 32; r += 8)
      Wt[(size_t)(c0 + ty + r) * D + k0 + tx] = f2bf(t[tx][ty + r]);
  }
}

// ---------------- QKV GEMM: [4096x1024] x [1024x3072] -------------
// 128x128 tile, BK=32, 2x2 waves of 64x64, 16x16x32 bf16 MFMA.
__global__ __launch_bounds__(256) void qkv_gemm_k(const unsigned short* __restrict__ xb,
                                                  const unsigned short* __restrict__ Wt,
                                                  unsigned short* __restrict__ qw,
                                                  unsigned short* __restrict__ kw,
                                                  unsigned short* __restrict__ vtw) {
  __shared__ unsigned short smA[128 * 32];
  __shared__ unsigned short smB[128 * 32];
  const int tid = threadIdx.x, w = tid >> 6, l = tid & 63;
  const int m0 = blockIdx.x * 128, n0 = blockIdx.y * 128;
  const int wm = w >> 1, wn = w & 1;

  const unsigned short* ga[2]; const unsigned short* gb[2];
  unsigned short* la[2]; unsigned short* lb[2];
#pragma unroll
  for (int i = 0; i < 2; ++i) {
    int idx = tid + i * 256;
    int row = idx >> 2;
    int blk = (idx & 3) ^ ((row >> 1) & 3);   // pre-swizzled global source
    ga[i] = xb + (size_t)(m0 + row) * D + blk * 8;
    gb[i] = Wt + (size_t)(n0 + row) * D + blk * 8;
    la[i] = smA + (w * 64 + i * 256) * 8;     // wave-uniform linear LDS dest
    lb[i] = smB + (w * 64 + i * 256) * 8;
  }

  f32x4 acc[4][4];
#pragma unroll
  for (int a = 0; a < 4; ++a)
#pragma unroll
    for (int b = 0; b < 4; ++b) acc[a][b] = (f32x4){0.f, 0.f, 0.f, 0.f};

  for (int kt = 0; kt < D / 32; ++kt) {
    __syncthreads();
#pragma unroll
    for (int i = 0; i < 2; ++i) {
      gload16(ga[i] + kt * 32, la[i]);
      gload16(gb[i] + kt * 32, lb[i]);
    }
    asm volatile("s_waitcnt vmcnt(0)" ::: "memory");
    __syncthreads();

    bf16x8 af[4], bfr[4];
#pragma unroll
    for (int a = 0; a < 4; ++a) {
      int arow = wm * 64 + a * 16 + (l & 15);
      int blk = (l >> 4) ^ ((arow >> 1) & 3);
      af[a] = *reinterpret_cast<const bf16x8*>(smA + arow * 32 + blk * 8);
    }
#pragma unroll
    for (int b = 0; b < 4; ++b) {
      int brow = wn * 64 + b * 16 + (l & 15);
      int blk = (l >> 4) ^ ((brow >> 1) & 3);
      bfr[b] = *reinterpret_cast<const bf16x8*>(smB + brow * 32 + blk * 8);
    }
#pragma unroll
    for (int a = 0; a < 4; ++a)
#pragma unroll
      for (int b = 0; b < 4; ++b)
        acc[a][b] = mfma16(af[a], bfr[b], acc[a][b]);
  }

  const int which = n0 >> 10;
#pragma unroll
  for (int a = 0; a < 4; ++a) {
#pragma unroll
    for (int b = 0; b < 4; ++b) {
#pragma unroll
      for (int r = 0; r < 4; ++r) {
        int grow = m0 + wm * 64 + a * 16 + (l >> 4) * 4 + r;
        int gcol = n0 + wn * 64 + b * 16 + (l & 15);
        float v = acc[a][b][r];
        int bb = grow >> 11, n = grow & 2047;
        int cc = gcol & 1023, h = cc >> 6, dh = cc & 63;
        size_t bh = (size_t)bb * NH + h;
        if (which == 0)
          qw[(bh * NSEQ + n) * 64 + dh] = f2bf(v * 0.18033688011112042f);
        else if (which == 1)
          kw[(bh * NSEQ + n) * 64 + dh] = f2bf(v);
        else
          vtw[(bh * 64 + dh) * NSEQ + n] = f2bf(v);
      }
    }
  }
}

// ---------------- causal flash attention: 8 waves, 4-way k-parity ---------
// 512 blocks = 8 XCD x 4 bh x 16 pairs {31-j, j}; every block = 9 supersteps.
// Block = 8 waves = 2 qsub (32 q-rows) x 4 parity (k-tiles t%4==par).
// Superstep: barrier | STAGE 4 K/V tiles (64KB single-buffer) | vmcnt(0) |
// barrier | wave computes tile 4s+par. 16 waves/CU (2 blocks) hide the
// QK->softmax->pack->PV serial chain. Segment end: 4-way LSE merge + LDS
// transpose (staging reused). In-reg P (cvt_pk+permlane32_swap), defer-max.
__global__ __launch_bounds__(512, 4) void attn_k(const unsigned short* __restrict__ qw,
                                                 const unsigned short* __restrict__ kw,
                                                 const unsigned short* __restrict__ vtw,
                                                 float* __restrict__ out) {
  __shared__ __align__(16) char lds[67584];  // 64KB stage (reused) + 2KB m/l
  const int tid = threadIdx.x, w = tid >> 6, l = tid & 63;
  const int hi = l >> 5, ql = l & 31;
  const int qsub = w >> 2, par = w & 3;

  const int wg = blockIdx.x;               // 512 blocks
  const int xcd = wg & 7, rest = wg >> 3;
  const int bhl = rest >> 4;               // local bh on this XCD
  const int j = rest & 15;                 // pair index
  const int bh = xcd * 4 + bhl;
  const int bb = bh >> 4, h = bh & 15;

  const unsigned short* qb = qw + (size_t)bh * NSEQ * 64;
  const unsigned short* kb = kw + (size_t)bh * NSEQ * 64;
  const unsigned short* vb = vtw + (size_t)bh * 64 * NSEQ;

  // staging: chunk C = i*512 + tid (i=0..7): tile T=i>>1, kv=i&1, idx=tid.
  // Source row sr = tid>>3, pre-swizzled chunk sc = (tid&7)^(sr&7).
  // LDS dest wave-uniform: buf(T,kv) + w*512 ushorts.
  const int sr = tid >> 3, sc = (tid & 7) ^ (sr & 7);

#define STAGE4(TB)                                                              \
  do {                                                                          \
    _Pragma("unroll")                                                           \
    for (int i_ = 0; i_ < 8; ++i_) {                                            \
      const int T_ = i_ >> 1, kv_ = i_ & 1;                                     \
      const int gt_ = (TB) + T_;                                                \
      if (gt_ <= qt) {                                                          \
        unsigned short* d_ =                                                    \
            (unsigned short*)(lds + T_ * 16384 + kv_ * 8192) + w * 512;         \
        if (kv_ == 0)                                                           \
          gload16(kb + ((size_t)(gt_ * 64 + sr) * 64 + sc * 8), d_);            \
        else                                                                    \
          gload16(vb + ((size_t)sr * NSEQ + gt_ * 64 + sc * 8), d_);            \
      }                                                                         \
    }                                                                           \
  } while (0)

  for (int seg = 0; seg < 2; ++seg) {
    const int qt = seg ? j : (31 - j);     // heavy q-tile first
    const int qbase = qt * 64;
    const int qg = qbase + qsub * 32 + ql; // this lane's q-row (global)

    bf16x8 qf[4];
#pragma unroll
    for (int ds = 0; ds < 4; ++ds)
      qf[ds] = *reinterpret_cast<const bf16x8*>(qb + (size_t)qg * 64 + ds * 16 + hi * 8);

    float m = -1e30f, lsum = 0.f;
    f32x16 O0, O1;
#pragma unroll
    for (int r2 = 0; r2 < 16; ++r2) { O0[r2] = 0.f; O1[r2] = 0.f; }

    const int nsup = (qt >> 2) + 1;
    for (int s = 0; s < nsup; ++s) {
      const int tb = 4 * s;
      __syncthreads();                     // prior reads of buffer done
      STAGE4(tb);
      asm volatile("s_waitcnt vmcnt(0)" ::: "memory");
      __syncthreads();                     // staged data visible

      const int t = tb + par;
      if (t <= qt) {
        const char* Kb = lds + par * 16384;
        const char* Vb = Kb + 8192;

        // QK: S^T[64k][32q], C rows=k, col q=ql
        f32x16 S0, S1;
#pragma unroll
        for (int r2 = 0; r2 < 16; ++r2) { S0[r2] = 0.f; S1[r2] = 0.f; }
        __builtin_amdgcn_s_setprio(1);
#pragma unroll
        for (int ds = 0; ds < 4; ++ds) {
          bf16x8 k0 = *reinterpret_cast<const bf16x8*>(
              Kb + ql * 128 + (((2 * ds + hi) ^ (ql & 7)) << 4));
          bf16x8 k1 = *reinterpret_cast<const bf16x8*>(
              Kb + (32 + ql) * 128 + (((2 * ds + hi) ^ (ql & 7)) << 4));
          S0 = mfma32(k0, qf[ds], S0);
          S1 = mfma32(k1, qf[ds], S1);
        }
        __builtin_amdgcn_s_setprio(0);

        if (t == qt) {  // causal mask on diagonal tile
#pragma unroll
          for (int reg = 0; reg < 16; ++reg) {
            const int krow = (reg & 3) + 8 * (reg >> 2) + 4 * hi;
            if (64 * t + krow > qg) S0[reg] = -1e30f;
            if (64 * t + 32 + krow > qg) S1[reg] = -1e30f;
          }
        }

        // row max: in-lane tree + one cross-half swap
        float t0 = fmaxf(S0[0], S1[0]), t1 = fmaxf(S0[1], S1[1]);
        float t2 = fmaxf(S0[2], S1[2]), t3 = fmaxf(S0[3], S1[3]);
#pragma unroll
        for (int r2 = 4; r2 < 16; r2 += 4) {
          t0 = fmaxf(t0, fmaxf(S0[r2], S1[r2]));
          t1 = fmaxf(t1, fmaxf(S0[r2 + 1], S1[r2 + 1]));
          t2 = fmaxf(t2, fmaxf(S0[r2 + 2], S1[r2 + 2]));
          t3 = fmaxf(t3, fmaxf(S0[r2 + 3], S1[r2 + 3]));
        }
        float tmax = xmax_halves(fmaxf(fmaxf(t0, t1), fmaxf(t2, t3)));

        if (!__all(tmax <= m + 8.0f)) {   // defer-max
          const float mn = fmaxf(m, tmax);
          const float g = exp2g(m - mn);
          m = mn;
          lsum *= g;
#pragma unroll
          for (int r2 = 0; r2 < 16; ++r2) { O0[r2] *= g; O1[r2] *= g; }
        }

        // exp in place + row sum
        float rA = 0.f, rB = 0.f, rC = 0.f, rD = 0.f;
#pragma unroll
        for (int r2 = 0; r2 < 16; r2 += 4) {
          S0[r2] = exp2g(S0[r2] - m);         S1[r2] = exp2g(S1[r2] - m);
          S0[r2 + 1] = exp2g(S0[r2 + 1] - m); S1[r2 + 1] = exp2g(S1[r2 + 1] - m);
          S0[r2 + 2] = exp2g(S0[r2 + 2] - m); S1[r2 + 2] = exp2g(S1[r2 + 2] - m);
          S0[r2 + 3] = exp2g(S0[r2 + 3] - m); S1[r2 + 3] = exp2g(S1[r2 + 3] - m);
          rA += S0[r2] + S1[r2];
          rB += S0[r2 + 1] + S1[r2 + 1];
          rC += S0[r2 + 2] + S1[r2 + 2];
          rD += S0[r2 + 3] + S1[r2 + 3];
        }
        {
          float rsum = (rA + rB) + (rC + rD);
          union { float f; unsigned int u; } c; c.f = rsum;
          u32x2 r = pswap2(c.u, c.u);
          union { unsigned int u; float f; } x, y; x.u = r.x; y.u = r.y;
          lsum += x.f + y.f;
        }

        // pack P into PV B-frags: cvt_pk + permlane32_swap
        bf16x8 pf[4];
#pragma unroll
        for (int ct = 0; ct < 2; ++ct) {
          unsigned int u[4][2];
#pragma unroll
          for (int c = 0; c < 4; ++c) {
            if (ct == 0) {
              u[c][0] = cvtpk(S0[4 * c], S0[4 * c + 1]);
              u[c][1] = cvtpk(S0[4 * c + 2], S0[4 * c + 3]);
            } else {
              u[c][0] = cvtpk(S1[4 * c], S1[4 * c + 1]);
              u[c][1] = cvtpk(S1[4 * c + 2], S1[4 * c + 3]);
            }
          }
#pragma unroll
          for (int kk = 0; kk < 2; ++kk) {
            u32x2 rw0 = pswap2(u[2 * kk][0], u[2 * kk + 1][0]);
            u32x2 rw1 = pswap2(u[2 * kk][1], u[2 * kk + 1][1]);
            U4 f;
            f.u[0] = rw0.x; f.u[1] = rw1.x;
            f.u[2] = rw0.y; f.u[3] = rw1.y;
            pf[2 * ct + kk] = f.v;
          }
        }

        // PV: O^T[64d][32q] += V^T-frag x P-frag
        __builtin_amdgcn_s_setprio(1);
#pragma unroll
        for (int ks = 0; ks < 4; ++ks) {
          bf16x8 v0 = *reinterpret_cast<const bf16x8*>(
              Vb + ql * 128 + (((2 * ks + hi) ^ (ql & 7)) << 4));
          bf16x8 v1 = *reinterpret_cast<const bf16x8*>(
              Vb + (32 + ql) * 128 + (((2 * ks + hi) ^ (ql & 7)) << 4));
          O0 = mfma32(v0, pf[ks], O0);
          O1 = mfma32(v1, pf[ks], O1);
        }
        __builtin_amdgcn_s_setprio(0);
      }
    }

    // ---- 4-way LSE merge across parities + epilogue ----
    __syncthreads();                       // all PV reads of staging done
    float* mlp = (float*)(lds + 65536);
    if (l < 32) { mlp[w * 64 + l] = m; mlp[w * 64 + 32 + l] = lsum; }
    __syncthreads();
    {
      float M = m, L = 0.f;
#pragma unroll
      for (int q = 0; q < 4; ++q)
        M = fmaxf(M, mlp[(qsub * 4 + q) * 64 + ql]);
#pragma unroll
      for (int q = 0; q < 4; ++q)
        L += mlp[(qsub * 4 + q) * 64 + 32 + ql] *
             exp2g(mlp[(qsub * 4 + q) * 64 + ql] - M);
      const float phi = exp2g(m - M) / L;
      float* mo = (float*)(lds + w * 8192);  // [32q][64d] swizzled, per wave
#pragma unroll
      for (int reg = 0; reg < 16; ++reg) {
        const int dr = (reg & 3) + 8 * (reg >> 2) + 4 * hi;
        const int d1 = 32 + dr;
        mo[ql * 64 + (((dr >> 2) ^ (ql & 7)) << 2) + (dr & 3)] = O0[reg] * phi;
        mo[ql * 64 + (((d1 >> 2) ^ (ql & 7)) << 2) + (d1 & 3)] = O1[reg] * phi;
      }
    }
    __syncthreads();
    {
      const int qq = tid >> 3;             // 0..63
      const int dq = (tid & 7) * 8;        // 8 floats per thread
      const int qsr = qq >> 5, qrow = qq & 31;
      float* op = out + ((size_t)bb * NSEQ + qbase + qq) * D + h * 64 + dq;
#pragma unroll
      for (int c2 = 0; c2 < 2; ++c2) {
        const int ch = ((dq >> 2) + c2) ^ (qrow & 7);
        float4 s4 = make_float4(0.f, 0.f, 0.f, 0.f);
#pragma unroll
        for (int p = 0; p < 4; ++p) {
          const float* bufp = (const float*)(lds + (qsr * 4 + p) * 8192);
          float4 v = *reinterpret_cast<const float4*>(bufp + qrow * 64 + ch * 4);
          s4.x += v.x; s4.y += v.y; s4.z += v.z; s4.w += v.w;
        }
        *reinterpret_cast<float4*>(op + c2 * 4) = s4;
      }
    }
    __syncthreads();   // protect LDS before next segment's STAGE
  }
#undef STAGE4
}

extern "C" void kernel_launch(void* const* d_in, const int* in_sizes, int n_in,
                              void* d_out, int out_size, void* d_ws, size_t ws_size,
                              hipStream_t stream) {
  const float* x = (const float*)d_in[0];
  const float* W = (const float*)d_in[1];
  float* out = (float*)d_out;
  char* ws = (char*)d_ws;
  unsigned short* xb  = (unsigned short*)(ws);               // 8 MB
  unsigned short* Wt  = (unsigned short*)(ws + 8388608);     // 6 MB
  unsigned short* qw  = (unsigned short*)(ws + 14680064);    // 8 MB
  unsigned short* kw  = (unsigned short*)(ws + 23068672);    // 8 MB
  unsigned short* vtw = (unsigned short*)(ws + 31457280);    // 8 MB

  prep_k<<<7168, 256, 0, stream>>>(x, W, xb, Wt);
  qkv_gemm_k<<<dim3(32, 24), 256, 0, stream>>>(xb, Wt, qw, kw, vtw);
  attn_k<<<512, 512, 0, stream>>>(qw, kw, vtw, out);
}